// Round 1
// baseline (150.127 us; speedup 1.0000x reference)
//
#include <hip/hip_runtime.h>

// GeometricLoss: N=8192 2-D points, C=16 outputs, k=5 nearest neighbors,
// result = mean over (i, 5 NN j) of ||outputs[i]-outputs[j]||_2.

static constexpr int NPTS = 8192;
static constexpr int KNN  = 5;
static constexpr int CH   = 16;
static constexpr int WPB  = 4;              // waves per block
static constexpr int NBLK = NPTS / WPB;     // 2048 blocks, 1 wave = 1 point

__device__ __forceinline__ unsigned long long shfl_xor_u64(unsigned long long v, int m) {
    unsigned int lo = (unsigned int)v;
    unsigned int hi = (unsigned int)(v >> 32);
    lo = __shfl_xor(lo, m, 64);
    hi = __shfl_xor(hi, m, 64);
    return ((unsigned long long)hi << 32) | lo;
}

__global__ __launch_bounds__(256, 8) void knn_loss_kernel(
        const float* __restrict__ outputs,
        const float* __restrict__ points,
        float* __restrict__ partial) {
    const int wave = threadIdx.x >> 6;
    const int lane = threadIdx.x & 63;
    const int i = blockIdx.x * WPB + wave;

    const float2 pi = ((const float2*)points)[i];
    const float sqi = pi.x * pi.x + pi.y * pi.y;

    const unsigned long long INF = ~0ull;
    // per-lane sorted ascending top-6 keys: (f32bits(d2)<<32)|j
    unsigned long long k0=INF, k1=INF, k2=INF, k3=INF, k4=INF, k5=INF;

    for (int j = lane; j < NPTS; j += 64) {
        const float2 pj = ((const float2*)points)[j];
        const float sqj = pj.x * pj.x + pj.y * pj.y;
        const float dot = pi.x * pj.x + pi.y * pj.y;
        float d2 = (sqi + sqj) - 2.0f * dot;
        d2 = fmaxf(d2, 0.0f);
        const unsigned long long key =
            ((unsigned long long)__float_as_uint(d2) << 32) | (unsigned int)j;
        if (key < k5) {
            k5 = key;
            unsigned long long t;
            if (k5 < k4) { t = k4; k4 = k5; k5 = t; }
            if (k4 < k3) { t = k3; k3 = k4; k4 = t; }
            if (k3 < k2) { t = k2; k2 = k3; k3 = t; }
            if (k2 < k1) { t = k1; k1 = k2; k2 = t; }
            if (k1 < k0) { t = k0; k0 = k1; k1 = t; }
        }
    }

    // Wave-wide: extract the 6 globally-smallest keys (keys are unique since
    // they embed j). Extraction 0 is the reference's dropped first column.
    unsigned int sel1 = 0, sel2 = 0, sel3 = 0, sel4 = 0, sel5 = 0;
    #pragma unroll
    for (int t = 0; t < KNN + 1; ++t) {
        unsigned long long m = k0;
        #pragma unroll
        for (int d = 1; d < 64; d <<= 1) {
            const unsigned long long v = shfl_xor_u64(m, d);
            if (v < m) m = v;
        }
        if (k0 == m) { k0 = k1; k1 = k2; k2 = k3; k3 = k4; k4 = k5; k5 = INF; }
        if      (t == 1) sel1 = (unsigned int)m;
        else if (t == 2) sel2 = (unsigned int)m;
        else if (t == 3) sel3 = (unsigned int)m;
        else if (t == 4) sel4 = (unsigned int)m;
        else if (t == 5) sel5 = (unsigned int)m;
    }

    // Lanes 1..5 each compute one neighbor's 16-channel L2 norm.
    float nrm = 0.0f;
    if (lane >= 1 && lane <= 5) {
        unsigned int j = sel1;
        if (lane == 2) j = sel2;
        if (lane == 3) j = sel3;
        if (lane == 4) j = sel4;
        if (lane == 5) j = sel5;
        const float4* oi = (const float4*)(outputs + (size_t)i * CH);
        const float4* oj = (const float4*)(outputs + (size_t)j * CH);
        float acc = 0.0f;
        #pragma unroll
        for (int q = 0; q < 4; ++q) {
            const float4 a = oi[q];
            const float4 b = oj[q];
            const float dx = a.x - b.x, dy = a.y - b.y;
            const float dz = a.z - b.z, dw = a.w - b.w;
            acc += dx * dx + dy * dy + dz * dz + dw * dw;
        }
        nrm = sqrtf(acc);
    }
    #pragma unroll
    for (int d = 1; d < 64; d <<= 1) nrm += __shfl_xor(nrm, d, 64);

    __shared__ float lds[WPB];
    if (lane == 0) lds[wave] = nrm;
    __syncthreads();
    if (threadIdx.x == 0)
        partial[blockIdx.x] = lds[0] + lds[1] + lds[2] + lds[3];
}

__global__ __launch_bounds__(256) void finalize_kernel(
        const float* __restrict__ partial, float* __restrict__ out) {
    double s = 0.0;
    for (int idx = threadIdx.x; idx < NBLK; idx += 256) s += (double)partial[idx];
    #pragma unroll
    for (int d = 1; d < 64; d <<= 1) s += __shfl_xor(s, d, 64);
    __shared__ double lds[4];
    const int wave = threadIdx.x >> 6;
    const int lane = threadIdx.x & 63;
    if (lane == 0) lds[wave] = s;
    __syncthreads();
    if (threadIdx.x == 0)
        out[0] = (float)((lds[0] + lds[1] + lds[2] + lds[3]) /
                         (double)((long long)NPTS * KNN));
}

extern "C" void kernel_launch(void* const* d_in, const int* in_sizes, int n_in,
                              void* d_out, int out_size, void* d_ws, size_t ws_size,
                              hipStream_t stream) {
    const float* outputs = (const float*)d_in[0];   // (8192, 16) f32
    const float* points  = (const float*)d_in[1];   // (8192, 2)  f32
    float* partial = (float*)d_ws;                  // NBLK floats of scratch
    float* out = (float*)d_out;

    knn_loss_kernel<<<NBLK, 256, 0, stream>>>(outputs, points, partial);
    finalize_kernel<<<1, 256, 0, stream>>>(partial, out);
}

// Round 2
// 125.934 us; speedup vs baseline: 1.1921x; 1.1921x over previous
//
#include <hip/hip_runtime.h>

// GeometricLoss: N=8192 2-D points, C=16 outputs, k=5 nearest neighbors,
// result = mean over (i, 5 NN j) of ||outputs[i]-outputs[j]||_2.
//
// Strategy: 1 wave per point. Pass 1: branchless per-lane min(d2) -> wave
// threshold T = 6th-smallest lane-min (guarantees >=6 candidates <= T).
// Pass 2: collect all (d2,j) keys with d2 <= T (rare, ~10-30 per point) into
// per-wave LDS, then extract the 6 lexicographically smallest u64 keys
// ((bits(d2)<<32)|j) which exactly replicates top_k's tie-break.

static constexpr int NPTS = 8192;
static constexpr int KNN  = 5;
static constexpr int CH   = 16;
static constexpr int WPB  = 4;              // waves per block
static constexpr int NBLK = NPTS / WPB;     // 2048 blocks, 1 wave = 1 point
static constexpr int CAP  = 128;            // per-wave candidate buffer

__device__ __forceinline__ unsigned long long shfl_xor_u64(unsigned long long v, int m) {
    unsigned int lo = (unsigned int)v;
    unsigned int hi = (unsigned int)(v >> 32);
    lo = __shfl_xor(lo, m, 64);
    hi = __shfl_xor(hi, m, 64);
    return ((unsigned long long)hi << 32) | lo;
}

// Pinned-fma distance so pass 1 and pass 2 are bit-identical.
__device__ __forceinline__ float dist2(float pix, float piy, float sqi,
                                       float pjx, float pjy) {
    const float sqj = fmaf(pjy, pjy, pjx * pjx);
    const float dot = fmaf(piy, pjy, pix * pjx);
    const float d2  = fmaf(-2.0f, dot, sqi + sqj);
    return fmaxf(d2, 0.0f);
}

__global__ __launch_bounds__(256, 8) void knn_loss_kernel(
        const float* __restrict__ outputs,
        const float* __restrict__ points,
        float* __restrict__ partial) {
    const int wave = threadIdx.x >> 6;
    const int lane = threadIdx.x & 63;
    const int i = blockIdx.x * WPB + wave;

    const float2 pi = ((const float2*)points)[i];
    const float sqi = fmaf(pi.y, pi.y, pi.x * pi.x);
    const float2* __restrict__ pts = (const float2*)points;

    // ---- Pass 1: per-lane min of d2 (branchless) ----
    float vmin = __int_as_float(0x7f800000);   // +inf
    #pragma unroll 8
    for (int j = lane; j < NPTS; j += 64) {
        const float2 pj = pts[j];
        vmin = fminf(vmin, dist2(pi.x, pi.y, sqi, pj.x, pj.y));
    }

    // T = 6th-smallest of the 64 lane minima (tie-collapse only shrinks T,
    // still leaves >=6 lanes with min <= T).
    float v = vmin, T = 0.0f;
    #pragma unroll
    for (int t = 0; t < KNN + 1; ++t) {
        float m = v;
        #pragma unroll
        for (int d = 1; d < 64; d <<= 1) m = fminf(m, __shfl_xor(m, d, 64));
        if (v == m) v = __int_as_float(0x7f800000);
        T = m;
    }

    // ---- Pass 2: collect keys with d2 <= T ----
    __shared__ unsigned long long buf[WPB][CAP];
    __shared__ int cnt[WPB];
    __shared__ float lds[WPB];
    if (lane == 0) cnt[wave] = 0;
    __syncthreads();

    #pragma unroll 8
    for (int j = lane; j < NPTS; j += 64) {
        const float2 pj = pts[j];
        const float d2 = dist2(pi.x, pi.y, sqi, pj.x, pj.y);
        if (d2 <= T) {
            const int pos = atomicAdd(&cnt[wave], 1);
            if (pos < CAP)
                buf[wave][pos] =
                    ((unsigned long long)__float_as_uint(d2) << 32) | (unsigned int)j;
        }
    }
    __syncthreads();

    // ---- Select 6 smallest u64 keys among collected ----
    const unsigned long long INF = ~0ull;
    const int n = min(cnt[wave], CAP);
    unsigned long long a = (lane      < n) ? buf[wave][lane]      : INF;
    unsigned long long b = (lane + 64 < n) ? buf[wave][lane + 64] : INF;
    if (b < a) { unsigned long long t = a; a = b; b = t; }

    unsigned int myj = 0;
    int active = 0;
    #pragma unroll
    for (int t = 0; t < KNN + 1; ++t) {
        unsigned long long m = a;
        #pragma unroll
        for (int d = 1; d < 64; d <<= 1) {
            const unsigned long long w = shfl_xor_u64(m, d);
            if (w < m) m = w;
        }
        if (a == m) { a = b; b = INF; }     // keys unique -> exactly one lane
        if (t >= 1 && lane == t) { myj = (unsigned int)m; active = 1; }
    }

    // Lanes 1..5 each compute one neighbor's 16-channel L2 norm.
    float nrm = 0.0f;
    if (active) {
        const float4* oi = (const float4*)(outputs + (size_t)i * CH);
        const float4* oj = (const float4*)(outputs + (size_t)myj * CH);
        float acc = 0.0f;
        #pragma unroll
        for (int q = 0; q < 4; ++q) {
            const float4 x = oi[q];
            const float4 y = oj[q];
            const float dx = x.x - y.x, dy = x.y - y.y;
            const float dz = x.z - y.z, dw = x.w - y.w;
            acc += dx * dx + dy * dy + dz * dz + dw * dw;
        }
        nrm = sqrtf(acc);
    }
    #pragma unroll
    for (int d = 1; d < 64; d <<= 1) nrm += __shfl_xor(nrm, d, 64);

    if (lane == 0) lds[wave] = nrm;
    __syncthreads();
    if (threadIdx.x == 0)
        partial[blockIdx.x] = lds[0] + lds[1] + lds[2] + lds[3];
}

__global__ __launch_bounds__(256) void finalize_kernel(
        const float* __restrict__ partial, float* __restrict__ out) {
    double s = 0.0;
    for (int idx = threadIdx.x; idx < NBLK; idx += 256) s += (double)partial[idx];
    #pragma unroll
    for (int d = 1; d < 64; d <<= 1) s += __shfl_xor(s, d, 64);
    __shared__ double lds[4];
    const int wave = threadIdx.x >> 6;
    const int lane = threadIdx.x & 63;
    if (lane == 0) lds[wave] = s;
    __syncthreads();
    if (threadIdx.x == 0)
        out[0] = (float)((lds[0] + lds[1] + lds[2] + lds[3]) /
                         (double)((long long)NPTS * KNN));
}

extern "C" void kernel_launch(void* const* d_in, const int* in_sizes, int n_in,
                              void* d_out, int out_size, void* d_ws, size_t ws_size,
                              hipStream_t stream) {
    const float* outputs = (const float*)d_in[0];   // (8192, 16) f32
    const float* points  = (const float*)d_in[1];   // (8192, 2)  f32
    float* partial = (float*)d_ws;                  // NBLK floats of scratch
    float* out = (float*)d_out;

    knn_loss_kernel<<<NBLK, 256, 0, stream>>>(outputs, points, partial);
    finalize_kernel<<<1, 256, 0, stream>>>(partial, out);
}

// Round 4
// 97.471 us; speedup vs baseline: 1.5402x; 1.2920x over previous
//
#include <hip/hip_runtime.h>

// GeometricLoss: N=8192 2-D points, C=16 outputs, k=5 nearest neighbors,
// result = mean over (i, 5 NN j) of ||outputs[i]-outputs[j]||_2.
//
// 1 wave per point. Pass 1: branchless per-lane min of RAW d2 (two
// accumulators, float4 = 2 points per load), clamp once at the end
// (clamp commutes with min). Wave threshold T = 6th-smallest clamped
// lane-min (>= true 6th-smallest distance -> >=6 candidates <= T).
// Pass 2: collect all (clamped d2, j) keys with raw d2 <= T (equivalent to
// clamped <= T since T >= 0) into per-wave LDS, then extract the 6
// lexicographically smallest u64 keys ((bits(d2)<<32)|j), replicating
// top_k's smaller-index tie-break. Both passes use the identical fmaf
// sequence so the threshold test is bit-exact.

static constexpr int NPTS = 8192;
static constexpr int KNN  = 5;
static constexpr int CH   = 16;
static constexpr int WPB  = 4;              // waves per block
static constexpr int NBLK = NPTS / WPB;     // 2048 blocks, 1 wave = 1 point
static constexpr int CAP  = 128;            // per-wave candidate buffer
static constexpr int NF4  = NPTS / 2;       // 4096 float4 = 2 points each

__device__ __forceinline__ unsigned long long shfl_xor_u64(unsigned long long v, int m) {
    unsigned int lo = (unsigned int)v;
    unsigned int hi = (unsigned int)(v >> 32);
    lo = __shfl_xor(lo, m, 64);
    hi = __shfl_xor(hi, m, 64);
    return ((unsigned long long)hi << 32) | lo;
}

__global__ __launch_bounds__(256, 8) void knn_loss_kernel(
        const float* __restrict__ outputs,
        const float* __restrict__ points,
        float* __restrict__ partial) {
    const int wave = threadIdx.x >> 6;
    const int lane = threadIdx.x & 63;
    const int i = blockIdx.x * WPB + wave;

    const float2 pi = ((const float2*)points)[i];
    const float4* __restrict__ pts4 = (const float4*)points;
    const float FINF = __int_as_float(0x7f800000);

    // ---- Pass 1: per-lane min of raw d2 (branchless, 2 candidates/iter) ----
    float vA = FINF, vB = FINF;
    #pragma unroll 8
    for (int it = lane; it < NF4; it += 64) {
        const float4 p = pts4[it];
        const float dxa = pi.x - p.x, dya = pi.y - p.y;
        const float dxb = pi.x - p.z, dyb = pi.y - p.w;
        const float d2a = fmaf(dxa, dxa, dya * dya);
        const float d2b = fmaf(dxb, dxb, dyb * dyb);
        vA = fminf(vA, d2a);
        vB = fminf(vB, d2b);
    }

    // T = 6th-smallest of the 64 clamped lane minima.
    float v = fmaxf(fminf(vA, vB), 0.0f);
    float T = 0.0f;
    #pragma unroll
    for (int t = 0; t < KNN + 1; ++t) {
        float m = v;
        #pragma unroll
        for (int d = 1; d < 64; d <<= 1) m = fminf(m, __shfl_xor(m, d, 64));
        if (v == m) v = FINF;
        T = m;
    }

    // ---- Pass 2: collect keys with raw d2 <= T ----
    __shared__ unsigned long long buf[WPB][CAP];
    __shared__ int cnt[WPB];
    __shared__ float lds[WPB];
    if (lane == 0) cnt[wave] = 0;
    __syncthreads();

    #pragma unroll 8
    for (int it = lane; it < NF4; it += 64) {
        const float4 p = pts4[it];
        const float dxa = pi.x - p.x, dya = pi.y - p.y;
        const float dxb = pi.x - p.z, dyb = pi.y - p.w;
        const float d2a = fmaf(dxa, dxa, dya * dya);
        const float d2b = fmaf(dxb, dxb, dyb * dyb);
        if (fminf(d2a, d2b) <= T) {
            if (d2a <= T) {
                const int pos = atomicAdd(&cnt[wave], 1);
                if (pos < CAP)
                    buf[wave][pos] = ((unsigned long long)__float_as_uint(fmaxf(d2a, 0.0f)) << 32)
                                     | (unsigned int)(2 * it);
            }
            if (d2b <= T) {
                const int pos = atomicAdd(&cnt[wave], 1);
                if (pos < CAP)
                    buf[wave][pos] = ((unsigned long long)__float_as_uint(fmaxf(d2b, 0.0f)) << 32)
                                     | (unsigned int)(2 * it + 1);
            }
        }
    }
    __syncthreads();

    // ---- Select the 6 smallest u64 keys among collected ----
    const unsigned long long INF = ~0ull;
    const int n = min(cnt[wave], CAP);
    unsigned long long a = (lane      < n) ? buf[wave][lane]      : INF;
    unsigned long long b = (lane + 64 < n) ? buf[wave][lane + 64] : INF;
    if (b < a) { unsigned long long t = a; a = b; b = t; }

    unsigned int myj = 0;
    int active = 0;
    #pragma unroll
    for (int t = 0; t < KNN + 1; ++t) {
        unsigned long long m = a;
        #pragma unroll
        for (int d = 1; d < 64; d <<= 1) {
            const unsigned long long w = shfl_xor_u64(m, d);
            if (w < m) m = w;
        }
        if (a == m) { a = b; b = INF; }     // keys unique -> exactly one lane
        if (t >= 1 && lane == t) { myj = (unsigned int)m; active = 1; }
    }

    // Lanes 1..5 each compute one neighbor's 16-channel L2 norm.
    float nrm = 0.0f;
    if (active) {
        const float4* oi = (const float4*)(outputs + (size_t)i * CH);
        const float4* oj = (const float4*)(outputs + (size_t)myj * CH);
        float acc = 0.0f;
        #pragma unroll
        for (int q = 0; q < 4; ++q) {
            const float4 x = oi[q];
            const float4 y = oj[q];
            const float dx = x.x - y.x, dy = x.y - y.y;
            const float dz = x.z - y.z, dw = x.w - y.w;
            acc += dx * dx + dy * dy + dz * dz + dw * dw;
        }
        nrm = sqrtf(acc);
    }
    #pragma unroll
    for (int d = 1; d < 64; d <<= 1) nrm += __shfl_xor(nrm, d, 64);

    if (lane == 0) lds[wave] = nrm;
    __syncthreads();
    if (threadIdx.x == 0)
        partial[blockIdx.x] = lds[0] + lds[1] + lds[2] + lds[3];
}

__global__ __launch_bounds__(256) void finalize_kernel(
        const float* __restrict__ partial, float* __restrict__ out) {
    double s = 0.0;
    for (int idx = threadIdx.x; idx < NBLK; idx += 256) s += (double)partial[idx];
    #pragma unroll
    for (int d = 1; d < 64; d <<= 1) s += __shfl_xor(s, d, 64);
    __shared__ double lds[4];
    const int wave = threadIdx.x >> 6;
    const int lane = threadIdx.x & 63;
    if (lane == 0) lds[wave] = s;
    __syncthreads();
    if (threadIdx.x == 0)
        out[0] = (float)((lds[0] + lds[1] + lds[2] + lds[3]) /
                         (double)((long long)NPTS * KNN));
}

extern "C" void kernel_launch(void* const* d_in, const int* in_sizes, int n_in,
                              void* d_out, int out_size, void* d_ws, size_t ws_size,
                              hipStream_t stream) {
    const float* outputs = (const float*)d_in[0];   // (8192, 16) f32
    const float* points  = (const float*)d_in[1];   // (8192, 2)  f32
    float* partial = (float*)d_ws;                  // NBLK floats of scratch
    float* out = (float*)d_out;

    knn_loss_kernel<<<NBLK, 256, 0, stream>>>(outputs, points, partial);
    finalize_kernel<<<1, 256, 0, stream>>>(partial, out);
}

// Round 5
// 95.386 us; speedup vs baseline: 1.5739x; 1.0219x over previous
//
#include <hip/hip_runtime.h>

// GeometricLoss: N=8192 2-D points, C=16 outputs, k=5 nearest neighbors,
// result = mean over (i, 5 NN j) of ||outputs[i]-outputs[j]||_2.
//
// 1 wave per point. Pass 1: branchless per-lane min of RAW d2 via v_min3
// (two accumulators, float4 = 2 points/load, 8 loads in flight), clamp once
// at the end. Wave threshold T = 6th-smallest clamped lane-min (>=6
// candidates <= T guaranteed). Pass 2: batches of 8 loads -> 16 d2s folded
// to a batch-min (min3 tree), single wave compare vs T; rare hit path
// recomputes d2 from live regs (bit-identical fmaf sequence) and collects
// (clamped d2, j) keys into per-wave LDS. Final: extract the 6
// lexicographically smallest u64 keys ((bits(d2)<<32)|j), replicating
// top_k's smaller-index tie-break; lanes 1..5 compute neighbor norms.

static constexpr int NPTS = 8192;
static constexpr int KNN  = 5;
static constexpr int CH   = 16;
static constexpr int WPB  = 4;              // waves per block
static constexpr int NBLK = NPTS / WPB;     // 2048 blocks, 1 wave = 1 point
static constexpr int CAP  = 128;            // per-wave candidate buffer
static constexpr int NF4  = NPTS / 2;       // 4096 float4 = 2 points each
static constexpr int BAT  = 8;              // loads per batch
static constexpr int NBAT = NF4 / (64 * BAT);  // 8 batches per lane

__device__ __forceinline__ unsigned long long shfl_xor_u64(unsigned long long v, int m) {
    unsigned int lo = (unsigned int)v;
    unsigned int hi = (unsigned int)(v >> 32);
    lo = __shfl_xor(lo, m, 64);
    hi = __shfl_xor(hi, m, 64);
    return ((unsigned long long)hi << 32) | lo;
}

__global__ __launch_bounds__(256, 8) void knn_loss_kernel(
        const float* __restrict__ outputs,
        const float* __restrict__ points,
        float* __restrict__ partial) {
    const int wave = threadIdx.x >> 6;
    const int lane = threadIdx.x & 63;
    const int i = blockIdx.x * WPB + wave;

    const float2 pi = ((const float2*)points)[i];
    const float4* __restrict__ pts4 = (const float4*)points;
    const float FINF = __int_as_float(0x7f800000);

    // ---- Pass 1: per-lane min of raw d2 (branchless, 8 loads deep) ----
    float vA = FINF, vB = FINF;
    for (int b = 0; b < NBAT; ++b) {
        float4 p[BAT];
        #pragma unroll
        for (int q = 0; q < BAT; ++q)
            p[q] = pts4[b * (64 * BAT) + q * 64 + lane];
        #pragma unroll
        for (int q = 0; q < BAT; ++q) {
            const float dxa = pi.x - p[q].x, dya = pi.y - p[q].y;
            const float dxb = pi.x - p[q].z, dyb = pi.y - p[q].w;
            const float d2a = fmaf(dxa, dxa, dya * dya);
            const float d2b = fmaf(dxb, dxb, dyb * dyb);
            if (q & 1) vB = fminf(fminf(vB, d2a), d2b);   // v_min3
            else       vA = fminf(fminf(vA, d2a), d2b);
        }
    }

    // T = 6th-smallest of the 64 clamped lane minima.
    float v = fmaxf(fminf(vA, vB), 0.0f);
    float T = 0.0f;
    #pragma unroll
    for (int t = 0; t < KNN + 1; ++t) {
        float m = v;
        #pragma unroll
        for (int d = 1; d < 64; d <<= 1) m = fminf(m, __shfl_xor(m, d, 64));
        if (v == m) v = FINF;
        T = m;
    }

    // ---- Pass 2: batched scan, rare collect of raw d2 <= T ----
    __shared__ unsigned long long buf[WPB][CAP];
    __shared__ int cnt[WPB];
    __shared__ float lds[WPB];
    if (lane == 0) cnt[wave] = 0;
    __syncthreads();

    for (int b = 0; b < NBAT; ++b) {
        float4 p[BAT];
        #pragma unroll
        for (int q = 0; q < BAT; ++q)
            p[q] = pts4[b * (64 * BAT) + q * 64 + lane];
        float bm = FINF;
        #pragma unroll
        for (int q = 0; q < BAT; ++q) {
            const float dxa = pi.x - p[q].x, dya = pi.y - p[q].y;
            const float dxb = pi.x - p[q].z, dyb = pi.y - p[q].w;
            const float d2a = fmaf(dxa, dxa, dya * dya);
            const float d2b = fmaf(dxb, dxb, dyb * dyb);
            bm = fminf(fminf(bm, d2a), d2b);               // v_min3
        }
        if (bm <= T) {                                     // rare (execz skip)
            #pragma unroll
            for (int q = 0; q < BAT; ++q) {
                const int it = b * (64 * BAT) + q * 64 + lane;
                const float dxa = pi.x - p[q].x, dya = pi.y - p[q].y;
                const float dxb = pi.x - p[q].z, dyb = pi.y - p[q].w;
                const float d2a = fmaf(dxa, dxa, dya * dya);
                const float d2b = fmaf(dxb, dxb, dyb * dyb);
                if (d2a <= T) {
                    const int pos = atomicAdd(&cnt[wave], 1);
                    if (pos < CAP)
                        buf[wave][pos] =
                            ((unsigned long long)__float_as_uint(fmaxf(d2a, 0.0f)) << 32)
                            | (unsigned int)(2 * it);
                }
                if (d2b <= T) {
                    const int pos = atomicAdd(&cnt[wave], 1);
                    if (pos < CAP)
                        buf[wave][pos] =
                            ((unsigned long long)__float_as_uint(fmaxf(d2b, 0.0f)) << 32)
                            | (unsigned int)(2 * it + 1);
                }
            }
        }
    }
    __syncthreads();

    // ---- Select the 6 smallest u64 keys among collected ----
    const unsigned long long INF = ~0ull;
    const int n = min(cnt[wave], CAP);
    unsigned long long a = (lane      < n) ? buf[wave][lane]      : INF;
    unsigned long long b = (lane + 64 < n) ? buf[wave][lane + 64] : INF;
    if (b < a) { unsigned long long t = a; a = b; b = t; }

    unsigned int myj = 0;
    int active = 0;
    #pragma unroll
    for (int t = 0; t < KNN + 1; ++t) {
        unsigned long long m = a;
        #pragma unroll
        for (int d = 1; d < 64; d <<= 1) {
            const unsigned long long w = shfl_xor_u64(m, d);
            if (w < m) m = w;
        }
        if (a == m) { a = b; b = INF; }     // keys unique -> exactly one lane
        if (t >= 1 && lane == t) { myj = (unsigned int)m; active = 1; }
    }

    // Lanes 1..5 each compute one neighbor's 16-channel L2 norm.
    float nrm = 0.0f;
    if (active) {
        const float4* oi = (const float4*)(outputs + (size_t)i * CH);
        const float4* oj = (const float4*)(outputs + (size_t)myj * CH);
        float acc = 0.0f;
        #pragma unroll
        for (int q = 0; q < 4; ++q) {
            const float4 x = oi[q];
            const float4 y = oj[q];
            const float dx = x.x - y.x, dy = x.y - y.y;
            const float dz = x.z - y.z, dw = x.w - y.w;
            acc += dx * dx + dy * dy + dz * dz + dw * dw;
        }
        nrm = sqrtf(acc);
    }
    #pragma unroll
    for (int d = 1; d < 64; d <<= 1) nrm += __shfl_xor(nrm, d, 64);

    if (lane == 0) lds[wave] = nrm;
    __syncthreads();
    if (threadIdx.x == 0)
        partial[blockIdx.x] = lds[0] + lds[1] + lds[2] + lds[3];
}

__global__ __launch_bounds__(256) void finalize_kernel(
        const float* __restrict__ partial, float* __restrict__ out) {
    double s = 0.0;
    for (int idx = threadIdx.x; idx < NBLK; idx += 256) s += (double)partial[idx];
    #pragma unroll
    for (int d = 1; d < 64; d <<= 1) s += __shfl_xor(s, d, 64);
    __shared__ double lds[4];
    const int wave = threadIdx.x >> 6;
    const int lane = threadIdx.x & 63;
    if (lane == 0) lds[wave] = s;
    __syncthreads();
    if (threadIdx.x == 0)
        out[0] = (float)((lds[0] + lds[1] + lds[2] + lds[3]) /
                         (double)((long long)NPTS * KNN));
}

extern "C" void kernel_launch(void* const* d_in, const int* in_sizes, int n_in,
                              void* d_out, int out_size, void* d_ws, size_t ws_size,
                              hipStream_t stream) {
    const float* outputs = (const float*)d_in[0];   // (8192, 16) f32
    const float* points  = (const float*)d_in[1];   // (8192, 2)  f32
    float* partial = (float*)d_ws;                  // NBLK floats of scratch
    float* out = (float*)d_out;

    knn_loss_kernel<<<NBLK, 256, 0, stream>>>(outputs, points, partial);
    finalize_kernel<<<1, 256, 0, stream>>>(partial, out);
}

// Round 6
// 93.518 us; speedup vs baseline: 1.6053x; 1.0200x over previous
//
#include <hip/hip_runtime.h>

// GeometricLoss: N=8192 2-D points, C=16 outputs, k=5 nearest neighbors,
// result = mean over (i, 5 NN j) of ||outputs[i]-outputs[j]||_2.
//
// Round-6 structure: the kernel is L2-BW-bound (1.07 GB of candidate reads
// at Q=1), so each wave now serves Q=4 queries from registers per loaded
// candidate float4 -> 4x less L2 traffic. 2048 waves (512 blocks x 4).
// Pass 1: per-lane per-query min of RAW d2 (min3 folding, 4 loads deep).
// T_q = 6th-smallest clamped lane-min (>= true 6th distance -> >=6
// candidates <= T_q; typically tight, collect count ~6-10).
// Pass 2: re-stream, rare per-query collect of (clamped d2, j) u64 keys
// ((bits(d2)<<32)|j) into per-(wave,query) LDS buffers; identical fmaf
// sequence both passes -> bit-exact threshold test.
// Select: per query extract the 6 lexicographically smallest keys
// (replicates top_k's smaller-index tie-break), drop the first (self),
// lanes q*8+1..q*8+5 compute the 16-channel neighbor norms.

static constexpr int NPTS  = 8192;
static constexpr int KNN   = 5;
static constexpr int CH    = 16;
static constexpr int WPB   = 4;               // waves per block
static constexpr int QPW   = 4;               // queries per wave
static constexpr int NWAVE = NPTS / QPW;      // 2048 waves
static constexpr int NBLK  = NWAVE / WPB;     // 512 blocks
static constexpr int CAP   = 128;             // per-(wave,query) buffer
static constexpr int NF4   = NPTS / 2;        // 4096 float4 = 2 points each
static constexpr int BAT   = 4;               // loads in flight
static constexpr int NIT   = NF4 / 64;        // 64 float4-iters per scan
static constexpr int NB    = NIT / BAT;       // 16 batches

__device__ __forceinline__ unsigned long long shfl_xor_u64(unsigned long long v, int m) {
    unsigned int lo = (unsigned int)v;
    unsigned int hi = (unsigned int)(v >> 32);
    lo = __shfl_xor(lo, m, 64);
    hi = __shfl_xor(hi, m, 64);
    return ((unsigned long long)hi << 32) | lo;
}

__global__ __launch_bounds__(256, 4) void knn_loss_kernel(
        const float* __restrict__ outputs,
        const float* __restrict__ points,
        float* __restrict__ partial) {
    const int wave  = threadIdx.x >> 6;
    const int lane  = threadIdx.x & 63;
    const int w     = blockIdx.x * WPB + wave;   // global wave id
    const int qbase = w * QPW;                   // first query of this wave

    const float2* __restrict__ pts2 = (const float2*)points;
    const float4* __restrict__ pts4 = (const float4*)points;
    const float FINF = __int_as_float(0x7f800000);

    float pix[QPW], piy[QPW];
    #pragma unroll
    for (int q = 0; q < QPW; ++q) {
        const float2 p = pts2[qbase + q];
        pix[q] = p.x; piy[q] = p.y;
    }

    // ---- Pass 1: per-lane per-query min of raw d2 (branchless) ----
    float acc[QPW];
    #pragma unroll
    for (int q = 0; q < QPW; ++q) acc[q] = FINF;

    for (int b = 0; b < NB; ++b) {
        float4 p[BAT];
        #pragma unroll
        for (int u = 0; u < BAT; ++u)
            p[u] = pts4[b * (BAT * 64) + u * 64 + lane];
        #pragma unroll
        for (int u = 0; u < BAT; ++u) {
            #pragma unroll
            for (int q = 0; q < QPW; ++q) {
                const float dxa = pix[q] - p[u].x, dya = piy[q] - p[u].y;
                const float dxb = pix[q] - p[u].z, dyb = piy[q] - p[u].w;
                const float d2a = fmaf(dxa, dxa, dya * dya);
                const float d2b = fmaf(dxb, dxb, dyb * dyb);
                acc[q] = fminf(fminf(acc[q], d2a), d2b);   // v_min3
            }
        }
    }

    // ---- T_q = 6th-smallest of 64 clamped lane-mins (query-interleaved) ----
    float v[QPW], T[QPW];
    #pragma unroll
    for (int q = 0; q < QPW; ++q) v[q] = fmaxf(acc[q], 0.0f);
    #pragma unroll
    for (int t = 0; t < KNN + 1; ++t) {
        float m[QPW];
        #pragma unroll
        for (int q = 0; q < QPW; ++q) m[q] = v[q];
        #pragma unroll
        for (int d = 1; d < 64; d <<= 1) {
            #pragma unroll
            for (int q = 0; q < QPW; ++q)
                m[q] = fminf(m[q], __shfl_xor(m[q], d, 64));
        }
        #pragma unroll
        for (int q = 0; q < QPW; ++q) {
            if (v[q] == m[q]) v[q] = FINF;
            T[q] = m[q];
        }
    }

    __shared__ unsigned long long buf[WPB][QPW][CAP];
    __shared__ int cnt[WPB][QPW];
    __shared__ float red[WPB];
    if (lane < QPW) cnt[wave][lane] = 0;
    __syncthreads();

    // ---- Pass 2: re-stream, rare per-query collect of raw d2 <= T_q ----
    for (int b = 0; b < NB; ++b) {
        float4 p[BAT];
        #pragma unroll
        for (int u = 0; u < BAT; ++u)
            p[u] = pts4[b * (BAT * 64) + u * 64 + lane];
        #pragma unroll
        for (int u = 0; u < BAT; ++u) {
            const int it = b * (BAT * 64) + u * 64 + lane;
            #pragma unroll
            for (int q = 0; q < QPW; ++q) {
                const float dxa = pix[q] - p[u].x, dya = piy[q] - p[u].y;
                const float dxb = pix[q] - p[u].z, dyb = piy[q] - p[u].w;
                const float d2a = fmaf(dxa, dxa, dya * dya);
                const float d2b = fmaf(dxb, dxb, dyb * dyb);
                if (d2a <= T[q] || d2b <= T[q]) {      // rare: execz skip
                    if (d2a <= T[q]) {
                        const int pos = atomicAdd(&cnt[wave][q], 1);
                        if (pos < CAP)
                            buf[wave][q][pos] =
                                ((unsigned long long)__float_as_uint(fmaxf(d2a, 0.0f)) << 32)
                                | (unsigned int)(2 * it);
                    }
                    if (d2b <= T[q]) {
                        const int pos = atomicAdd(&cnt[wave][q], 1);
                        if (pos < CAP)
                            buf[wave][q][pos] =
                                ((unsigned long long)__float_as_uint(fmaxf(d2b, 0.0f)) << 32)
                                | (unsigned int)(2 * it + 1);
                    }
                }
            }
        }
    }
    __syncthreads();

    // ---- Per query: select the 6 smallest u64 keys among collected ----
    const unsigned long long INF64 = ~0ull;
    unsigned int myj = 0;
    int myi = 0, active = 0;
    #pragma unroll
    for (int q = 0; q < QPW; ++q) {
        const int n = min(cnt[wave][q], CAP);
        unsigned long long a  = (lane      < n) ? buf[wave][q][lane]      : INF64;
        unsigned long long b2 = (lane + 64 < n) ? buf[wave][q][lane + 64] : INF64;
        if (b2 < a) { unsigned long long t = a; a = b2; b2 = t; }
        #pragma unroll
        for (int t = 0; t < KNN + 1; ++t) {
            unsigned long long m = a;
            #pragma unroll
            for (int d = 1; d < 64; d <<= 1) {
                const unsigned long long x = shfl_xor_u64(m, d);
                if (x < m) m = x;
            }
            if (a == m) { a = b2; b2 = INF64; }   // keys unique
            if (t >= 1 && lane == q * 8 + t) {
                myj = (unsigned int)m; myi = qbase + q; active = 1;
            }
        }
    }

    // ---- 20 active lanes compute the (query, neighbor) norms ----
    float nrm = 0.0f;
    if (active) {
        const float4* oi = (const float4*)(outputs + (size_t)myi * CH);
        const float4* oj = (const float4*)(outputs + (size_t)myj * CH);
        float s = 0.0f;
        #pragma unroll
        for (int c = 0; c < 4; ++c) {
            const float4 x = oi[c], y = oj[c];
            const float dx = x.x - y.x, dy = x.y - y.y;
            const float dz = x.z - y.z, dw = x.w - y.w;
            s += dx * dx + dy * dy + dz * dz + dw * dw;
        }
        nrm = sqrtf(s);
    }
    #pragma unroll
    for (int d = 1; d < 64; d <<= 1) nrm += __shfl_xor(nrm, d, 64);

    if (lane == 0) red[wave] = nrm;
    __syncthreads();
    if (threadIdx.x == 0)
        partial[blockIdx.x] = red[0] + red[1] + red[2] + red[3];
}

__global__ __launch_bounds__(256) void finalize_kernel(
        const float* __restrict__ partial, float* __restrict__ out) {
    double s = 0.0;
    for (int idx = threadIdx.x; idx < NBLK; idx += 256) s += (double)partial[idx];
    #pragma unroll
    for (int d = 1; d < 64; d <<= 1) s += __shfl_xor(s, d, 64);
    __shared__ double lds[4];
    const int wave = threadIdx.x >> 6;
    const int lane = threadIdx.x & 63;
    if (lane == 0) lds[wave] = s;
    __syncthreads();
    if (threadIdx.x == 0)
        out[0] = (float)((lds[0] + lds[1] + lds[2] + lds[3]) /
                         (double)((long long)NPTS * KNN));
}

extern "C" void kernel_launch(void* const* d_in, const int* in_sizes, int n_in,
                              void* d_out, int out_size, void* d_ws, size_t ws_size,
                              hipStream_t stream) {
    const float* outputs = (const float*)d_in[0];   // (8192, 16) f32
    const float* points  = (const float*)d_in[1];   // (8192, 2)  f32
    float* partial = (float*)d_ws;                  // NBLK floats of scratch
    float* out = (float*)d_out;

    knn_loss_kernel<<<NBLK, 256, 0, stream>>>(outputs, points, partial);
    finalize_kernel<<<1, 256, 0, stream>>>(partial, out);
}

// Round 7
// 84.815 us; speedup vs baseline: 1.7700x; 1.1026x over previous
//
#include <hip/hip_runtime.h>

// GeometricLoss: N=8192 2-D points, C=16 outputs, k=5 nearest neighbors,
// result = mean over (i, 5 NN j) of ||outputs[i]-outputs[j]||_2.
//
// Round-7 structure: Q=4 queries per BLOCK (register-held), scanned
// cooperatively by all 256 threads -> keeps the 4x L2-traffic reduction of
// round 6 while restoring 8192 waves (32/CU) for latency hiding.
// Pass 1: per-thread per-query min of RAW d2 (min3 folding, 4 loads deep,
// each thread scans 32 candidates). Clamped per-thread minima go to LDS;
// wave w extracts T_w = 6th-distinct-smallest of 64 lane values (lane =
// min of 4 thread minima via ds_read_b128) -> >=6 candidates <= T_w
// guaranteed (distinct lanes contribute distinct candidates).
// Pass 2: re-stream with the IDENTICAL fmaf sequence; single fold
// g = min_q(min(d2a,d2b) - T[q]) -> one rare branch per float4 (IEEE sub
// sign is exact: no false negatives); rare body does exact per-query
// compares and collects (clamped-d2, j) u64 keys ((bits<<32)|j) into
// block-shared per-query buffers.
// Select: wave w extracts the 6 smallest keys of query w (replicating
// top_k's smaller-index tie-break), drops the first (self column), lanes
// 1..5 compute the 16-channel neighbor norms.

static constexpr int NPTS    = 8192;
static constexpr int KNN     = 5;
static constexpr int CH      = 16;
static constexpr int QPB     = 4;                // queries per block (= waves)
static constexpr int THREADS = 256;
static constexpr int NBLK    = NPTS / QPB;       // 2048 blocks
static constexpr int CAP     = 128;              // per-query candidate buffer
static constexpr int NF4     = NPTS / 2;         // 4096 float4 = 2 points each
static constexpr int ITERS   = NF4 / THREADS;    // 16 float4 per thread
static constexpr int BAT     = 4;                // loads in flight
static constexpr int NB      = ITERS / BAT;      // 4 batches

__device__ __forceinline__ unsigned long long shfl_xor_u64(unsigned long long v, int m) {
    unsigned int lo = (unsigned int)v;
    unsigned int hi = (unsigned int)(v >> 32);
    lo = __shfl_xor(lo, m, 64);
    hi = __shfl_xor(hi, m, 64);
    return ((unsigned long long)hi << 32) | lo;
}

__global__ __launch_bounds__(256, 8) void knn_loss_kernel(
        const float* __restrict__ outputs,
        const float* __restrict__ points,
        float* __restrict__ partial) {
    const int tid  = threadIdx.x;
    const int wave = tid >> 6;
    const int lane = tid & 63;
    const int qbase = blockIdx.x * QPB;

    const float2* __restrict__ pts2 = (const float2*)points;
    const float4* __restrict__ pts4 = (const float4*)points;
    const float FINF = __int_as_float(0x7f800000);

    float pix[QPB], piy[QPB];
    #pragma unroll
    for (int q = 0; q < QPB; ++q) {
        const float2 p = pts2[qbase + q];
        pix[q] = p.x; piy[q] = p.y;
    }

    // ---- Pass 1: per-thread per-query min of raw d2 (branchless) ----
    float acc[QPB];
    #pragma unroll
    for (int q = 0; q < QPB; ++q) acc[q] = FINF;

    for (int b = 0; b < NB; ++b) {
        float4 p[BAT];
        #pragma unroll
        for (int u = 0; u < BAT; ++u)
            p[u] = pts4[b * (BAT * THREADS) + u * THREADS + tid];
        #pragma unroll
        for (int u = 0; u < BAT; ++u) {
            #pragma unroll
            for (int q = 0; q < QPB; ++q) {
                const float dxa = pix[q] - p[u].x, dya = piy[q] - p[u].y;
                const float dxb = pix[q] - p[u].z, dyb = piy[q] - p[u].w;
                const float d2a = fmaf(dxa, dxa, dya * dya);
                const float d2b = fmaf(dxb, dxb, dyb * dyb);
                acc[q] = fminf(fminf(acc[q], d2a), d2b);   // v_min3
            }
        }
    }

    // ---- Block-level thresholds via LDS ----
    __shared__ float thrmin[QPB][THREADS];
    __shared__ unsigned long long buf[QPB][CAP];
    __shared__ int cnt[QPB];
    __shared__ float Ts[QPB];
    __shared__ float red[QPB];

    #pragma unroll
    for (int q = 0; q < QPB; ++q)
        thrmin[q][tid] = fmaxf(acc[q], 0.0f);      // clamped per-thread min
    if (tid < QPB) cnt[tid] = 0;
    __syncthreads();

    // Wave w: T_w = 6th-distinct-smallest of 64 lane pre-mins for query w.
    {
        const float4 tv = ((const float4*)thrmin[wave])[lane];
        float v = fminf(fminf(tv.x, tv.y), fminf(tv.z, tv.w));
        float T = 0.0f;
        #pragma unroll
        for (int t = 0; t < KNN + 1; ++t) {
            float m = v;
            #pragma unroll
            for (int d = 1; d < 64; d <<= 1) m = fminf(m, __shfl_xor(m, d, 64));
            if (v == m) v = FINF;
            T = m;
        }
        if (lane == 0) Ts[wave] = T;
    }
    __syncthreads();

    float Tq[QPB];
    #pragma unroll
    for (int q = 0; q < QPB; ++q) Tq[q] = Ts[q];

    // ---- Pass 2: re-stream, rare collect of raw d2 <= T_q ----
    for (int b = 0; b < NB; ++b) {
        float4 p[BAT];
        #pragma unroll
        for (int u = 0; u < BAT; ++u)
            p[u] = pts4[b * (BAT * THREADS) + u * THREADS + tid];
        #pragma unroll
        for (int u = 0; u < BAT; ++u) {
            const int it = b * (BAT * THREADS) + u * THREADS + tid;
            float g = FINF;
            #pragma unroll
            for (int q = 0; q < QPB; ++q) {
                const float dxa = pix[q] - p[u].x, dya = piy[q] - p[u].y;
                const float dxb = pix[q] - p[u].z, dyb = piy[q] - p[u].w;
                const float d2a = fmaf(dxa, dxa, dya * dya);
                const float d2b = fmaf(dxb, dxb, dyb * dyb);
                g = fminf(g, fminf(d2a, d2b) - Tq[q]);
            }
            if (g <= 0.0f) {                         // rare: execz skip
                #pragma unroll
                for (int q = 0; q < QPB; ++q) {
                    const float dxa = pix[q] - p[u].x, dya = piy[q] - p[u].y;
                    const float dxb = pix[q] - p[u].z, dyb = piy[q] - p[u].w;
                    const float d2a = fmaf(dxa, dxa, dya * dya);
                    const float d2b = fmaf(dxb, dxb, dyb * dyb);
                    if (d2a <= Tq[q]) {
                        const int pos = atomicAdd(&cnt[q], 1);
                        if (pos < CAP)
                            buf[q][pos] =
                                ((unsigned long long)__float_as_uint(fmaxf(d2a, 0.0f)) << 32)
                                | (unsigned int)(2 * it);
                    }
                    if (d2b <= Tq[q]) {
                        const int pos = atomicAdd(&cnt[q], 1);
                        if (pos < CAP)
                            buf[q][pos] =
                                ((unsigned long long)__float_as_uint(fmaxf(d2b, 0.0f)) << 32)
                                | (unsigned int)(2 * it + 1);
                    }
                }
            }
        }
    }
    __syncthreads();

    // ---- Wave w: select the 6 smallest keys for query w ----
    const unsigned long long INF64 = ~0ull;
    const int n = min(cnt[wave], CAP);
    unsigned long long a  = (lane      < n) ? buf[wave][lane]      : INF64;
    unsigned long long b2 = (lane + 64 < n) ? buf[wave][lane + 64] : INF64;
    if (b2 < a) { unsigned long long t = a; a = b2; b2 = t; }

    unsigned int myj = 0;
    int active = 0;
    #pragma unroll
    for (int t = 0; t < KNN + 1; ++t) {
        unsigned long long m = a;
        #pragma unroll
        for (int d = 1; d < 64; d <<= 1) {
            const unsigned long long x = shfl_xor_u64(m, d);
            if (x < m) m = x;
        }
        if (a == m) { a = b2; b2 = INF64; }   // keys unique -> one lane drops
        if (t >= 1 && lane == t) { myj = (unsigned int)m; active = 1; }
    }

    // ---- Lanes 1..5 of wave w: neighbor norms for query qbase+w ----
    float nrm = 0.0f;
    if (active) {
        const float4* oi = (const float4*)(outputs + (size_t)(qbase + wave) * CH);
        const float4* oj = (const float4*)(outputs + (size_t)myj * CH);
        float s = 0.0f;
        #pragma unroll
        for (int c = 0; c < 4; ++c) {
            const float4 x = oi[c], y = oj[c];
            const float dx = x.x - y.x, dy = x.y - y.y;
            const float dz = x.z - y.z, dw = x.w - y.w;
            s += dx * dx + dy * dy + dz * dz + dw * dw;
        }
        nrm = sqrtf(s);
    }
    #pragma unroll
    for (int d = 1; d < 64; d <<= 1) nrm += __shfl_xor(nrm, d, 64);

    if (lane == 0) red[wave] = nrm;
    __syncthreads();
    if (tid == 0)
        partial[blockIdx.x] = red[0] + red[1] + red[2] + red[3];
}

__global__ __launch_bounds__(256) void finalize_kernel(
        const float* __restrict__ partial, float* __restrict__ out) {
    double s = 0.0;
    for (int idx = threadIdx.x; idx < NBLK; idx += 256) s += (double)partial[idx];
    #pragma unroll
    for (int d = 1; d < 64; d <<= 1) s += __shfl_xor(s, d, 64);
    __shared__ double lds[4];
    const int wave = threadIdx.x >> 6;
    const int lane = threadIdx.x & 63;
    if (lane == 0) lds[wave] = s;
    __syncthreads();
    if (threadIdx.x == 0)
        out[0] = (float)((lds[0] + lds[1] + lds[2] + lds[3]) /
                         (double)((long long)NPTS * KNN));
}

extern "C" void kernel_launch(void* const* d_in, const int* in_sizes, int n_in,
                              void* d_out, int out_size, void* d_ws, size_t ws_size,
                              hipStream_t stream) {
    const float* outputs = (const float*)d_in[0];   // (8192, 16) f32
    const float* points  = (const float*)d_in[1];   // (8192, 2)  f32
    float* partial = (float*)d_ws;                  // NBLK floats of scratch
    float* out = (float*)d_out;

    knn_loss_kernel<<<NBLK, THREADS, 0, stream>>>(outputs, points, partial);
    finalize_kernel<<<1, 256, 0, stream>>>(partial, out);
}